// Round 12
// baseline (275.456 us; speedup 1.0000x reference)
//
#include <hip/hip_runtime.h>

#define N_NODES 50000
#define N_EDGES 800000
#define BN_EPS 1e-5f
#define NB 196          // dst buckets: bucket = dst >> 8
#define BCAP 5120       // bucket capacity (avg 4082, sigma ~64)
#define SCAT_BLOCKS 400 // 2000 edges per block
#define EPB 2000

typedef __bf16 bf16x8 __attribute__((ext_vector_type(8)));
typedef float f32x4 __attribute__((ext_vector_type(4)));

static __device__ __forceinline__ unsigned short f2b(float f) {
    unsigned int u = __float_as_uint(f);
    return (unsigned short)((u + 0x7FFFu + ((u >> 16) & 1u)) >> 16);   // RNE
}
static __device__ __forceinline__ float bl(unsigned int u) { return __uint_as_float(u << 16); }
static __device__ __forceinline__ float bh(unsigned int u) { return __uint_as_float(u & 0xFFFF0000u); }

// ---------------------------------------------------------------------------
// CSR build via dense-write bucket sort
// ---------------------------------------------------------------------------
__global__ void init_gcur(int* __restrict__ gcur) {
    int t = threadIdx.x;
    if (t < NB) gcur[t] = t * BCAP;
}

__global__ __launch_bounds__(256) void bucket_scatter(const int* __restrict__ ei,
                                                      int* __restrict__ gcur,
                                                      unsigned int* __restrict__ bdata) {
    __shared__ int hist[NB];
    __shared__ int lcur[NB];
    int t = threadIdx.x;
    if (t < NB) hist[t] = 0;
    __syncthreads();
    int e0 = blockIdx.x * EPB;
    for (int i = t; i < EPB; i += 256) {
        int d = ei[N_EDGES + e0 + i];
        atomicAdd(&hist[d >> 8], 1);
    }
    __syncthreads();
    if (t < NB) lcur[t] = atomicAdd(&gcur[t], hist[t]);
    __syncthreads();
    for (int i = t; i < EPB; i += 256) {
        int d = ei[N_EDGES + e0 + i];
        int s = ei[e0 + i];
        int b = d >> 8;
        int p = atomicAdd(&lcur[b], 1);
        if (p < (b + 1) * BCAP)                       // capacity guard
            bdata[p] = (unsigned int)s | ((unsigned int)(d & 255) << 16);
    }
}

__global__ __launch_bounds__(256) void scan_buckets(const int* __restrict__ gcur,
                                                    int* __restrict__ bbase,
                                                    int* __restrict__ row) {
    __shared__ int sm[256];
    int t = threadIdx.x;
    int v = 0;
    if (t < NB) {
        v = gcur[t] - t * BCAP;
        if (v > BCAP) v = BCAP;
    }
    sm[t] = v;
    __syncthreads();
    int x = v;
    for (int off = 1; off < 256; off <<= 1) {
        int y = (t >= off) ? sm[t - off] : 0;
        __syncthreads();
        x += y;
        sm[t] = x;
        __syncthreads();
    }
    if (t < NB) bbase[t] = x - v;   // exclusive
    if (t == 0) row[N_NODES] = N_EDGES;
}

__global__ __launch_bounds__(256) void bucket_fill(const unsigned int* __restrict__ bdata,
                                                   const int* __restrict__ gcur,
                                                   const int* __restrict__ bbase,
                                                   int* __restrict__ row,
                                                   int* __restrict__ csrc) {
    __shared__ unsigned int ent[BCAP];
    __shared__ int lcnt[256];
    __shared__ int sm[256];
    __shared__ int cur[256];
    int b = blockIdx.x;
    int t = threadIdx.x;
    int cnt = gcur[b] - b * BCAP;
    if (cnt > BCAP) cnt = BCAP;
    int base = bbase[b];
    for (int i = t; i < cnt; i += 256) ent[i] = bdata[b * BCAP + i];
    lcnt[t] = 0;
    __syncthreads();
    for (int i = t; i < cnt; i += 256) atomicAdd(&lcnt[(ent[i] >> 16) & 255], 1);
    __syncthreads();
    int v = lcnt[t];
    sm[t] = v;
    __syncthreads();
    int x = v;
    for (int off = 1; off < 256; off <<= 1) {
        int y = (t >= off) ? sm[t - off] : 0;
        __syncthreads();
        x += y;
        sm[t] = x;
        __syncthreads();
    }
    int pre = x - v;
    int node = b * 256 + t;
    if (node < N_NODES) row[node] = base + pre;
    cur[t] = base + pre;
    __syncthreads();
    for (int i = t; i < cnt; i += 256) {
        unsigned int e = ent[i];
        int p = atomicAdd(&cur[(e >> 16) & 255], 1);
        csrc[p] = (int)(e & 0xFFFFu);
    }
}

// ---------------------------------------------------------------------------
// Casts / weight fragment packing
// ---------------------------------------------------------------------------
__global__ __launch_bounds__(256) void cast_x(const float* __restrict__ in,
                                              unsigned short* __restrict__ out) {
    int idx = blockIdx.x * 256 + threadIdx.x;          // float4 chunk
    if (idx >= N_NODES * 32) return;
    float4 v = ((const float4*)in)[idx];
    uint2 p;
    p.x = (unsigned int)f2b(v.x) | ((unsigned int)f2b(v.y) << 16);
    p.y = (unsigned int)f2b(v.z) | ((unsigned int)f2b(v.w) << 16);
    ((uint2*)out)[idx] = p;
}

// Pack [Wl|Wr] rows (K=256) into MFMA-fragment order:
// wp[(((o>>4)*8 + kc)*64 + ko*16 + (o&15))*8 + (k&7)], kc=k>>5, ko=(k>>3)&3
__global__ void wpack(const float* __restrict__ Wl1, const float* __restrict__ Wr1,
                      const float* __restrict__ Wl2, const float* __restrict__ Wr2,
                      const float* __restrict__ Wl3, const float* __restrict__ Wr3,
                      unsigned short* __restrict__ wp) {
    int idx = blockIdx.x * 256 + threadIdx.x;
    if (idx >= 81920) return;
    const float *Wl, *Wr;
    int rel, base;
    if (idx < 32768)       { Wl = Wl1; Wr = Wr1; rel = idx;         base = 0; }
    else if (idx < 65536)  { Wl = Wl2; Wr = Wr2; rel = idx - 32768; base = 32768; }
    else                   { Wl = Wl3; Wr = Wr3; rel = idx - 65536; base = 65536; }
    int o = rel >> 8;          // output col
    int k = rel & 255;         // k index in [Wl|Wr]
    float v = (k < 128) ? Wl[o * 128 + k] : Wr[o * 128 + (k - 128)];
    int nfAll = o >> 4, lr = o & 15;
    int kc = k >> 5, ko = (k >> 3) & 3, kj = k & 7;
    int lane = ko * 16 + lr;
    wp[base + (((nfAll * 8 + kc) * 64 + lane) << 3) + kj] = f2b(v);
}

// ---------------------------------------------------------------------------
// Mean aggregation: half-wave (32 lanes) per node.
// ACT: apply relu(h*scale+shift) to each gathered element (prev layer BN).
// ---------------------------------------------------------------------------
template <bool ACT>
__global__ __launch_bounds__(256) void agg_mean_bf16(const unsigned short* __restrict__ xin,
                                                     const int* __restrict__ row,
                                                     const int* __restrict__ csrc,
                                                     const float* __restrict__ scl,
                                                     const float* __restrict__ shf,
                                                     unsigned short* __restrict__ mean) {
    int half = threadIdx.x >> 5;
    int hl = threadIdx.x & 31;
    int node = blockIdx.x * 8 + half;
    if (node >= N_NODES) return;
    float4 sc{}, sh{};
    if (ACT) {
        sc = ((const float4*)scl)[hl];
        sh = ((const float4*)shf)[hl];
    }
    int r0 = row[node], r1 = row[node + 1];
    const uint2* x2 = (const uint2*)xin;   // row stride 32 uint2
    float a0 = 0.f, a1 = 0.f, a2 = 0.f, a3 = 0.f;
    auto val = [&](float raw, float s, float h) {
        return ACT ? fmaxf(fmaf(raw, s, h), 0.f) : raw;
    };
    int j = r0;
    for (; j + 1 < r1; j += 2) {
        int s0 = csrc[j];
        int s1 = csrc[j + 1];
        uint2 v0 = x2[(size_t)s0 * 32 + hl];
        uint2 v1 = x2[(size_t)s1 * 32 + hl];
        a0 += val(bl(v0.x), sc.x, sh.x) + val(bl(v1.x), sc.x, sh.x);
        a1 += val(bh(v0.x), sc.y, sh.y) + val(bh(v1.x), sc.y, sh.y);
        a2 += val(bl(v0.y), sc.z, sh.z) + val(bl(v1.y), sc.z, sh.z);
        a3 += val(bh(v0.y), sc.w, sh.w) + val(bh(v1.y), sc.w, sh.w);
    }
    if (j < r1) {
        uint2 v = x2[(size_t)csrc[j] * 32 + hl];
        a0 += val(bl(v.x), sc.x, sh.x);
        a1 += val(bh(v.x), sc.y, sh.y);
        a2 += val(bl(v.y), sc.z, sh.z);
        a3 += val(bh(v.y), sc.w, sh.w);
    }
    int deg = r1 - r0;
    float inv = 1.0f / (float)(deg > 1 ? deg : 1);
    uint2 pk;
    pk.x = (unsigned int)f2b(a0 * inv) | ((unsigned int)f2b(a1 * inv) << 16);
    pk.y = (unsigned int)f2b(a2 * inv) | ((unsigned int)f2b(a3 * inv) << 16);
    ((uint2*)mean)[(size_t)node * 32 + hl] = pk;
}

// ---------------------------------------------------------------------------
// MFMA dual-GEMM, wave-autonomous with asm-forced parallel loads.
// Block = 256 thr = 32 rows x 64 cols; wave = 16 rows x 32 cols.
// 24 global_load_dwordx4 per lane issued via inline asm (all in flight),
// one vmcnt(0) + sched_barrier, 16 MFMAs, epilogue. No A/W LDS, no stage
// barrier -> agg-like TLP/MLP regime (the R9 structure minus hipcc's
// register-minimizing serialization).
// ---------------------------------------------------------------------------
template <int O, bool BF16OUT, bool STATS, bool ACTX>
__global__ __launch_bounds__(256) void gemm_mfma(const unsigned short* __restrict__ Am,
                                                 const unsigned short* __restrict__ Ax,
                                                 const unsigned short* __restrict__ wp,
                                                 const float* __restrict__ bias,
                                                 const float* __restrict__ sclx,
                                                 const float* __restrict__ shfx,
                                                 unsigned short* __restrict__ hout,
                                                 float* __restrict__ fout,
                                                 float* __restrict__ cs,
                                                 float* __restrict__ cq) {
    constexpr int CH = O / 64;               // col 64-groups
    __shared__ float colsum[64], colsq[64];
    int t = threadIdx.x;
    int wv = t >> 6, l = t & 63;
    int lr = l & 15, ko = l >> 4;

    int rb = (CH == 2) ? (blockIdx.x >> 1) : blockIdx.x;
    int ch = (CH == 2) ? (blockIdx.x & 1) : 0;
    int rbase = rb * 32;
    int cb0 = ch * 64;

    if (STATS) {
        if (t < 64) {
            colsum[t] = 0.f;
            colsq[t] = 0.f;
        }
        __syncthreads();
    }

    int arow = rbase + (wv >> 1) * 16 + lr;
    if (arow >= N_NODES) arow = N_NODES - 1;
    int nfb = ch * 4 + (wv & 1) * 2;         // 16-col fragment group base
    int cbase = nfb * 16;                    // wave's global col base

    // ---- 24 asm-forced parallel loads: 8 A frags + 16 W frags ----
    const unsigned short* am = Am + (size_t)arow * 128 + ko * 8;
    const unsigned short* ax = Ax + (size_t)arow * 128 + ko * 8;
    const unsigned short* wb = wp + (size_t)nfb * 4096 + l * 8;   // 8*512 per nf
    uint4 amr[4], axr[4], wfr[2][8];
#pragma unroll
    for (int ks = 0; ks < 4; ++ks) {
        asm volatile("global_load_dwordx4 %0, %1, off"
                     : "=v"(amr[ks]) : "v"(am + ks * 32));
        asm volatile("global_load_dwordx4 %0, %1, off"
                     : "=v"(axr[ks]) : "v"(ax + ks * 32));
    }
#pragma unroll
    for (int nf = 0; nf < 2; ++nf)
#pragma unroll
        for (int kc = 0; kc < 8; ++kc) {
            asm volatile("global_load_dwordx4 %0, %1, off"
                         : "=v"(wfr[nf][kc]) : "v"(wb + (nf * 8 + kc) * 512));
        }
    asm volatile("s_waitcnt vmcnt(0)" ::: "memory");
    __builtin_amdgcn_sched_barrier(0);

    // ---- fused prev-layer BN+ReLU on self fragments ----
    if (ACTX) {
#pragma unroll
        for (int ks = 0; ks < 4; ++ks) {
            int f0 = ks * 32 + ko * 8;
            float4 s0 = *(const float4*)(sclx + f0);
            float4 s1 = *(const float4*)(sclx + f0 + 4);
            float4 h0 = *(const float4*)(shfx + f0);
            float4 h1 = *(const float4*)(shfx + f0 + 4);
            uint4 u = axr[ks];
            uint4 r;
            float e0 = fmaxf(fmaf(bl(u.x), s0.x, h0.x), 0.f);
            float e1 = fmaxf(fmaf(bh(u.x), s0.y, h0.y), 0.f);
            float e2 = fmaxf(fmaf(bl(u.y), s0.z, h0.z), 0.f);
            float e3 = fmaxf(fmaf(bh(u.y), s0.w, h0.w), 0.f);
            float e4 = fmaxf(fmaf(bl(u.z), s1.x, h1.x), 0.f);
            float e5 = fmaxf(fmaf(bh(u.z), s1.y, h1.y), 0.f);
            float e6 = fmaxf(fmaf(bl(u.w), s1.z, h1.z), 0.f);
            float e7 = fmaxf(fmaf(bh(u.w), s1.w, h1.w), 0.f);
            r.x = (unsigned int)f2b(e0) | ((unsigned int)f2b(e1) << 16);
            r.y = (unsigned int)f2b(e2) | ((unsigned int)f2b(e3) << 16);
            r.z = (unsigned int)f2b(e4) | ((unsigned int)f2b(e5) << 16);
            r.w = (unsigned int)f2b(e6) | ((unsigned int)f2b(e7) << 16);
            axr[ks] = r;
        }
    }

    // ---- 16 MFMAs ----
    f32x4 acc[2];
    acc[0] = (f32x4){0.f, 0.f, 0.f, 0.f};
    acc[1] = (f32x4){0.f, 0.f, 0.f, 0.f};
#pragma unroll
    for (int kc = 0; kc < 8; ++kc) {
        uint4 au = (kc < 4) ? amr[kc] : axr[kc - 4];
        bf16x8 af = *(bf16x8*)&au;
#pragma unroll
        for (int nf = 0; nf < 2; ++nf) {
            bf16x8 wf = *(bf16x8*)&wfr[nf][kc];
            acc[nf] = __builtin_amdgcn_mfma_f32_16x16x32_bf16(af, wf, acc[nf], 0, 0, 0);
        }
    }

    // ---- epilogue: bias + store + fused column stats ----
    int orow0 = rbase + (wv >> 1) * 16 + ko * 4;
#pragma unroll
    for (int nf = 0; nf < 2; ++nf) {
        int col = cbase + nf * 16 + lr;
        float bs = bias[col];
        float s = 0.f, q = 0.f;
#pragma unroll
        for (int j = 0; j < 4; ++j) {
            int r = orow0 + j;
            if (r < N_NODES) {
                float v = acc[nf][j] + bs;
                if (BF16OUT) hout[(size_t)r * 128 + col] = f2b(v);
                else         fout[(size_t)r * 64 + col] = v;
                s += v;
                q += v * v;
            }
        }
        if (STATS) {
            s += __shfl_xor(s, 16);
            s += __shfl_xor(s, 32);
            q += __shfl_xor(q, 16);
            q += __shfl_xor(q, 32);
            if (ko == 0) {
                atomicAdd(&colsum[col - cb0], s);
                atomicAdd(&colsq[col - cb0], q);
            }
        }
    }
    if (STATS) {
        __syncthreads();
        if (t < 64) {
            atomicAdd(&cs[cb0 + t], colsum[t]);
            atomicAdd(&cq[cb0 + t], colsq[t]);
        }
    }
}

__global__ void bn_prep(const float* __restrict__ cs, const float* __restrict__ cq,
                        const float* __restrict__ g, const float* __restrict__ be,
                        float* __restrict__ scale, float* __restrict__ shift) {
    int f = threadIdx.x;
    float mu = cs[f] * (1.0f / N_NODES);
    float var = cq[f] * (1.0f / N_NODES) - mu * mu;
    float sc = g[f] * rsqrtf(var + BN_EPS);
    scale[f] = sc;
    shift[f] = be[f] - mu * sc;
}

// ---------------------------------------------------------------------------
extern "C" void kernel_launch(void* const* d_in, const int* in_sizes, int n_in,
                              void* d_out, int out_size, void* d_ws, size_t ws_size,
                              hipStream_t stream) {
    const float* x   = (const float*)d_in[0];
    const int*   ei  = (const int*)d_in[1];
    const float* Wl1 = (const float*)d_in[2];
    const float* Wr1 = (const float*)d_in[3];
    const float* b1  = (const float*)d_in[4];
    const float* g1  = (const float*)d_in[5];
    const float* be1 = (const float*)d_in[6];
    const float* Wl2 = (const float*)d_in[7];
    const float* Wr2 = (const float*)d_in[8];
    const float* b2  = (const float*)d_in[9];
    const float* g2  = (const float*)d_in[10];
    const float* be2 = (const float*)d_in[11];
    const float* Wl3 = (const float*)d_in[12];
    const float* Wr3 = (const float*)d_in[13];
    const float* b3  = (const float*)d_in[14];
    float* out = (float*)d_out;

    char* p = (char*)d_ws;
    size_t off = 0;
    auto alloc = [&](size_t bytes) {
        char* r = p + off;
        off = (off + bytes + 255) & ~(size_t)255;
        return r;
    };
    int*            gcur  = (int*)alloc((size_t)NB * 4);
    int*            bbase = (int*)alloc((size_t)NB * 4);
    unsigned int*   bdata = (unsigned int*)alloc((size_t)NB * BCAP * 4);
    int*            row   = (int*)alloc((size_t)(N_NODES + 1) * 4);
    int*            csrc  = (int*)alloc((size_t)N_EDGES * 4);
    unsigned short* xb    = (unsigned short*)alloc((size_t)N_NODES * 128 * 2);
    unsigned short* mn    = (unsigned short*)alloc((size_t)N_NODES * 128 * 2);
    unsigned short* h1    = (unsigned short*)alloc((size_t)N_NODES * 128 * 2);
    unsigned short* h2    = (unsigned short*)alloc((size_t)N_NODES * 128 * 2);
    unsigned short* wpb   = (unsigned short*)alloc((size_t)81920 * 2);
    float*          cs    = (float*)alloc(256 * 4);   // cs[128] | cq[128]
    float*          cq    = cs + 128;
    float*          scl1  = (float*)alloc(128 * 4);
    float*          shf1  = (float*)alloc(128 * 4);
    float*          scl2  = (float*)alloc(128 * 4);
    float*          shf2  = (float*)alloc(128 * 4);
    (void)ws_size; (void)n_in; (void)in_sizes; (void)out_size;

    unsigned short* wp1 = wpb;
    unsigned short* wp2 = wpb + 32768;
    unsigned short* wp3 = wpb + 65536;

    const int NBLK8 = (N_NODES + 7) / 8;            // 6250
    const int RB32  = (N_NODES + 31) / 32;          // 1563 row-blocks
    const int CBLK  = (N_NODES * 32 + 255) / 256;   // 6250

    // casts + weight packing + CSR build
    cast_x<<<CBLK, 256, 0, stream>>>(x, xb);
    wpack<<<320, 256, 0, stream>>>(Wl1, Wr1, Wl2, Wr2, Wl3, Wr3, wpb);
    init_gcur<<<1, 256, 0, stream>>>(gcur);
    bucket_scatter<<<SCAT_BLOCKS, 256, 0, stream>>>(ei, gcur, bdata);
    scan_buckets<<<1, 256, 0, stream>>>(gcur, bbase, row);
    bucket_fill<<<NB, 256, 0, stream>>>(bdata, gcur, bbase, row, csrc);

    // Layer 1
    agg_mean_bf16<false><<<NBLK8, 256, 0, stream>>>(xb, row, csrc, nullptr, nullptr, mn);
    hipMemsetAsync(cs, 0, 256 * 4, stream);
    gemm_mfma<128, true, true, false><<<RB32 * 2, 256, 0, stream>>>(
        mn, xb, wp1, b1, nullptr, nullptr, h1, nullptr, cs, cq);
    bn_prep<<<1, 128, 0, stream>>>(cs, cq, g1, be1, scl1, shf1);

    // Layer 2 (h1 raw; BN1+ReLU fused into agg + gemm self-path)
    agg_mean_bf16<true><<<NBLK8, 256, 0, stream>>>(h1, row, csrc, scl1, shf1, mn);
    hipMemsetAsync(cs, 0, 256 * 4, stream);
    gemm_mfma<128, true, true, true><<<RB32 * 2, 256, 0, stream>>>(
        mn, h1, wp2, b2, scl1, shf1, h2, nullptr, cs, cq);
    bn_prep<<<1, 128, 0, stream>>>(cs, cq, g2, be2, scl2, shf2);

    // Layer 3 (h2 raw; BN2+ReLU fused) -> f32 d_out
    agg_mean_bf16<true><<<NBLK8, 256, 0, stream>>>(h2, row, csrc, scl2, shf2, mn);
    gemm_mfma<64, false, false, true><<<RB32, 256, 0, stream>>>(
        mn, h2, wp3, b3, scl2, shf2, nullptr, out, nullptr, nullptr);
}

// Round 13
// 229.146 us; speedup vs baseline: 1.2021x; 1.2021x over previous
//
#include <hip/hip_runtime.h>

#define N_NODES 50000
#define N_EDGES 800000
#define BN_EPS 1e-5f
#define NB 196          // dst buckets: bucket = dst >> 8
#define BCAP 5120       // bucket capacity (avg 4082, sigma ~64)
#define SCAT_BLOCKS 400 // 2000 edges per block
#define EPB 2000
#define GGRID 391       // 782 row-tiles = 2 x 391

typedef __bf16 bf16x8 __attribute__((ext_vector_type(8)));
typedef float f32x4 __attribute__((ext_vector_type(4)));

static __device__ __forceinline__ unsigned short f2b(float f) {
    unsigned int u = __float_as_uint(f);
    return (unsigned short)((u + 0x7FFFu + ((u >> 16) & 1u)) >> 16);   // RNE
}
static __device__ __forceinline__ float bl(unsigned int u) { return __uint_as_float(u << 16); }
static __device__ __forceinline__ float bh(unsigned int u) { return __uint_as_float(u & 0xFFFF0000u); }

// async global->LDS, 16B per lane, no dest VGPRs
static __device__ __forceinline__ void gload16(const void* g, void* l) {
    __builtin_amdgcn_global_load_lds(
        (const __attribute__((address_space(1))) unsigned int*)g,
        (__attribute__((address_space(3))) unsigned int*)l, 16, 0, 0);
}

// ---------------------------------------------------------------------------
// CSR build via dense-write bucket sort
// ---------------------------------------------------------------------------
__global__ void init_gcur(int* __restrict__ gcur) {
    int t = threadIdx.x;
    if (t < NB) gcur[t] = t * BCAP;
}

__global__ __launch_bounds__(256) void bucket_scatter(const int* __restrict__ ei,
                                                      int* __restrict__ gcur,
                                                      unsigned int* __restrict__ bdata) {
    __shared__ int hist[NB];
    __shared__ int lcur[NB];
    int t = threadIdx.x;
    if (t < NB) hist[t] = 0;
    __syncthreads();
    int e0 = blockIdx.x * EPB;
    for (int i = t; i < EPB; i += 256) {
        int d = ei[N_EDGES + e0 + i];
        atomicAdd(&hist[d >> 8], 1);
    }
    __syncthreads();
    if (t < NB) lcur[t] = atomicAdd(&gcur[t], hist[t]);
    __syncthreads();
    for (int i = t; i < EPB; i += 256) {
        int d = ei[N_EDGES + e0 + i];
        int s = ei[e0 + i];
        int b = d >> 8;
        int p = atomicAdd(&lcur[b], 1);
        if (p < (b + 1) * BCAP)                       // capacity guard
            bdata[p] = (unsigned int)s | ((unsigned int)(d & 255) << 16);
    }
}

__global__ __launch_bounds__(256) void scan_buckets(const int* __restrict__ gcur,
                                                    int* __restrict__ bbase,
                                                    int* __restrict__ row) {
    __shared__ int sm[256];
    int t = threadIdx.x;
    int v = 0;
    if (t < NB) {
        v = gcur[t] - t * BCAP;
        if (v > BCAP) v = BCAP;
    }
    sm[t] = v;
    __syncthreads();
    int x = v;
    for (int off = 1; off < 256; off <<= 1) {
        int y = (t >= off) ? sm[t - off] : 0;
        __syncthreads();
        x += y;
        sm[t] = x;
        __syncthreads();
    }
    if (t < NB) bbase[t] = x - v;   // exclusive
    if (t == 0) row[N_NODES] = N_EDGES;
}

__global__ __launch_bounds__(256) void bucket_fill(const unsigned int* __restrict__ bdata,
                                                   const int* __restrict__ gcur,
                                                   const int* __restrict__ bbase,
                                                   int* __restrict__ row,
                                                   int* __restrict__ csrc) {
    __shared__ unsigned int ent[BCAP];
    __shared__ int lcnt[256];
    __shared__ int sm[256];
    __shared__ int cur[256];
    int b = blockIdx.x;
    int t = threadIdx.x;
    int cnt = gcur[b] - b * BCAP;
    if (cnt > BCAP) cnt = BCAP;
    int base = bbase[b];
    for (int i = t; i < cnt; i += 256) ent[i] = bdata[b * BCAP + i];
    lcnt[t] = 0;
    __syncthreads();
    for (int i = t; i < cnt; i += 256) atomicAdd(&lcnt[(ent[i] >> 16) & 255], 1);
    __syncthreads();
    int v = lcnt[t];
    sm[t] = v;
    __syncthreads();
    int x = v;
    for (int off = 1; off < 256; off <<= 1) {
        int y = (t >= off) ? sm[t - off] : 0;
        __syncthreads();
        x += y;
        sm[t] = x;
        __syncthreads();
    }
    int pre = x - v;
    int node = b * 256 + t;
    if (node < N_NODES) row[node] = base + pre;
    cur[t] = base + pre;
    __syncthreads();
    for (int i = t; i < cnt; i += 256) {
        unsigned int e = ent[i];
        int p = atomicAdd(&cur[(e >> 16) & 255], 1);
        csrc[p] = (int)(e & 0xFFFFu);
    }
}

// ---------------------------------------------------------------------------
// Casts / weight fragment packing
// ---------------------------------------------------------------------------
__global__ __launch_bounds__(256) void cast_x(const float* __restrict__ in,
                                              unsigned short* __restrict__ out) {
    int idx = blockIdx.x * 256 + threadIdx.x;          // float4 chunk
    if (idx >= N_NODES * 32) return;
    float4 v = ((const float4*)in)[idx];
    uint2 p;
    p.x = (unsigned int)f2b(v.x) | ((unsigned int)f2b(v.y) << 16);
    p.y = (unsigned int)f2b(v.z) | ((unsigned int)f2b(v.w) << 16);
    ((uint2*)out)[idx] = p;
}

// Pack [Wl|Wr] rows (K=256) into MFMA-fragment order:
// wp[(((o>>4)*8 + kc)*64 + ko*16 + (o&15))*8 + (k&7)], kc=k>>5, ko=(k>>3)&3
__global__ void wpack(const float* __restrict__ Wl1, const float* __restrict__ Wr1,
                      const float* __restrict__ Wl2, const float* __restrict__ Wr2,
                      const float* __restrict__ Wl3, const float* __restrict__ Wr3,
                      unsigned short* __restrict__ wp) {
    int idx = blockIdx.x * 256 + threadIdx.x;
    if (idx >= 81920) return;
    const float *Wl, *Wr;
    int rel, base;
    if (idx < 32768)       { Wl = Wl1; Wr = Wr1; rel = idx;         base = 0; }
    else if (idx < 65536)  { Wl = Wl2; Wr = Wr2; rel = idx - 32768; base = 32768; }
    else                   { Wl = Wl3; Wr = Wr3; rel = idx - 65536; base = 65536; }
    int o = rel >> 8;          // output col
    int k = rel & 255;         // k index in [Wl|Wr]
    float v = (k < 128) ? Wl[o * 128 + k] : Wr[o * 128 + (k - 128)];
    int nfAll = o >> 4, lr = o & 15;
    int kc = k >> 5, ko = (k >> 3) & 3, kj = k & 7;
    int lane = ko * 16 + lr;
    wp[base + (((nfAll * 8 + kc) * 64 + lane) << 3) + kj] = f2b(v);
}

// ---------------------------------------------------------------------------
// Mean aggregation: half-wave (32 lanes) per node.
// ACT: apply relu(h*scale+shift) to each gathered element (prev layer BN).
// ---------------------------------------------------------------------------
template <bool ACT>
__global__ __launch_bounds__(256) void agg_mean_bf16(const unsigned short* __restrict__ xin,
                                                     const int* __restrict__ row,
                                                     const int* __restrict__ csrc,
                                                     const float* __restrict__ scl,
                                                     const float* __restrict__ shf,
                                                     unsigned short* __restrict__ mean) {
    int half = threadIdx.x >> 5;
    int hl = threadIdx.x & 31;
    int node = blockIdx.x * 8 + half;
    if (node >= N_NODES) return;
    float4 sc{}, sh{};
    if (ACT) {
        sc = ((const float4*)scl)[hl];
        sh = ((const float4*)shf)[hl];
    }
    int r0 = row[node], r1 = row[node + 1];
    const uint2* x2 = (const uint2*)xin;   // row stride 32 uint2
    float a0 = 0.f, a1 = 0.f, a2 = 0.f, a3 = 0.f;
    auto val = [&](float raw, float s, float h) {
        return ACT ? fmaxf(fmaf(raw, s, h), 0.f) : raw;
    };
    int j = r0;
    for (; j + 1 < r1; j += 2) {
        int s0 = csrc[j];
        int s1 = csrc[j + 1];
        uint2 v0 = x2[(size_t)s0 * 32 + hl];
        uint2 v1 = x2[(size_t)s1 * 32 + hl];
        a0 += val(bl(v0.x), sc.x, sh.x) + val(bl(v1.x), sc.x, sh.x);
        a1 += val(bh(v0.x), sc.y, sh.y) + val(bh(v1.x), sc.y, sh.y);
        a2 += val(bl(v0.y), sc.z, sh.z) + val(bl(v1.y), sc.z, sh.z);
        a3 += val(bh(v0.y), sc.w, sh.w) + val(bh(v1.y), sc.w, sh.w);
    }
    if (j < r1) {
        uint2 v = x2[(size_t)csrc[j] * 32 + hl];
        a0 += val(bl(v.x), sc.x, sh.x);
        a1 += val(bh(v.x), sc.y, sh.y);
        a2 += val(bl(v.y), sc.z, sh.z);
        a3 += val(bh(v.y), sc.w, sh.w);
    }
    int deg = r1 - r0;
    float inv = 1.0f / (float)(deg > 1 ? deg : 1);
    uint2 pk;
    pk.x = (unsigned int)f2b(a0 * inv) | ((unsigned int)f2b(a1 * inv) << 16);
    pk.y = (unsigned int)f2b(a2 * inv) | ((unsigned int)f2b(a3 * inv) << 16);
    ((uint2*)mean)[(size_t)node * 32 + hl] = pk;
}

// ---------------------------------------------------------------------------
// MFMA dual-GEMM, T3 minimum-2-phase pipeline:
// grid 391, block = 2 row-tiles of 64 rows x O cols. A double-buffered in LDS
// (2x32KB, async gload_lds, XOR-swizzled source); W in registers (wave owns
// O/4 cols = NFW frags x 8 kc). STAGE(t1) overlaps COMPUTE(t0); one barrier
// per tile. Stats in regs across tiles -> 2 atomics/col/block at end.
// ---------------------------------------------------------------------------
template <int O, bool BF16OUT, bool STATS, bool ACTX>
__global__ __launch_bounds__(256, 1) void gemm_mfma(const unsigned short* __restrict__ Am,
                                                    const unsigned short* __restrict__ Ax,
                                                    const unsigned short* __restrict__ wp,
                                                    const float* __restrict__ bias,
                                                    const float* __restrict__ sclx,
                                                    const float* __restrict__ shfx,
                                                    unsigned short* __restrict__ hout,
                                                    float* __restrict__ fout,
                                                    float* __restrict__ cs,
                                                    float* __restrict__ cq) {
    constexpr int NFW = O / 64;              // col-frags per wave (128->2, 64->1)
    __shared__ uint4 abuf[4096];             // 2 x 32KB A double-buffer
    char* lds = (char*)abuf;
    int t = threadIdx.x;
    int wv = t >> 6, l = t & 63;
    int lr = l & 15, ko = l >> 4;

    int t0 = blockIdx.x;                     // tiles t0 and t0+GGRID (782 exact)
    int t1 = t0 + GGRID;

    // ---- W fragments -> registers (one-time, L2-hot packed stream) ----
    uint4 wfr[NFW][8];
#pragma unroll
    for (int nf = 0; nf < NFW; ++nf)
#pragma unroll
        for (int kc = 0; kc < 8; ++kc)
            wfr[nf][kc] = *(const uint4*)(wp + (size_t)(((wv * NFW + nf) * 8 + kc) * 512) + l * 8);

    float sacc[NFW], qacc[NFW];
#pragma unroll
    for (int nf = 0; nf < NFW; ++nf) { sacc[nf] = 0.f; qacc[nf] = 0.f; }

    // ---- async stage of one 64-row tile into buffer buf ----
    auto STAGE = [&](int buf, int tile) {
        int rbase = tile * 64;
        char* bdst = lds + buf * 32768;
#pragma unroll
        for (int i = 0; i < 8; ++i) {
            int sb = wv * 8 + i;             // 0..31: <16 mn, else x
            int half = sb >> 4;
            int rloc = (sb & 15) * 4 + (l >> 4);
            int grow = rbase + rloc;
            if (grow >= N_NODES) grow = N_NODES - 1;
            int clog = (l & 15) ^ (rloc & 7);   // inverse-swizzled source
            const unsigned short* src = half ? Ax : Am;
            gload16(src + (size_t)grow * 128 + clog * 8, bdst + sb * 1024);
        }
    };

    // ---- compute + epilogue for the tile in buffer buf ----
    auto COMPUTE = [&](int buf, int tile) {
        const char* ab = lds + buf * 32768;
        f32x4 acc[4][NFW];
#pragma unroll
        for (int rt = 0; rt < 4; ++rt)
#pragma unroll
            for (int nf = 0; nf < NFW; ++nf) acc[rt][nf] = (f32x4){0.f, 0.f, 0.f, 0.f};

#pragma unroll
        for (int kc = 0; kc < 8; ++kc) {
            int clog = (kc & 3) * 4 + ko;
            float4 s0{}, s1{}, h0{}, h1{};
            if (ACTX && kc >= 4) {
                int f0 = clog * 8;
                s0 = *(const float4*)(sclx + f0);
                s1 = *(const float4*)(sclx + f0 + 4);
                h0 = *(const float4*)(shfx + f0);
                h1 = *(const float4*)(shfx + f0 + 4);
            }
#pragma unroll
            for (int rt = 0; rt < 4; ++rt) {
                int rloc = rt * 16 + lr;
                int cphys = clog ^ (rloc & 7);
                bf16x8 af = *(const bf16x8*)(ab + (kc >> 2) * 16384 + rloc * 256 + cphys * 16);
                if (ACTX && kc >= 4) {       // fused prev-layer BN+ReLU on self
                    uint4 u = *(uint4*)&af;
                    uint4 r;
                    float e0 = fmaxf(fmaf(bl(u.x), s0.x, h0.x), 0.f);
                    float e1 = fmaxf(fmaf(bh(u.x), s0.y, h0.y), 0.f);
                    float e2 = fmaxf(fmaf(bl(u.y), s0.z, h0.z), 0.f);
                    float e3 = fmaxf(fmaf(bh(u.y), s0.w, h0.w), 0.f);
                    float e4 = fmaxf(fmaf(bl(u.z), s1.x, h1.x), 0.f);
                    float e5 = fmaxf(fmaf(bh(u.z), s1.y, h1.y), 0.f);
                    float e6 = fmaxf(fmaf(bl(u.w), s1.z, h1.z), 0.f);
                    float e7 = fmaxf(fmaf(bh(u.w), s1.w, h1.w), 0.f);
                    r.x = (unsigned int)f2b(e0) | ((unsigned int)f2b(e1) << 16);
                    r.y = (unsigned int)f2b(e2) | ((unsigned int)f2b(e3) << 16);
                    r.z = (unsigned int)f2b(e4) | ((unsigned int)f2b(e5) << 16);
                    r.w = (unsigned int)f2b(e6) | ((unsigned int)f2b(e7) << 16);
                    af = *(bf16x8*)&r;
                }
#pragma unroll
                for (int nf = 0; nf < NFW; ++nf) {
                    bf16x8 wf = *(bf16x8*)&wfr[nf][kc];
                    acc[rt][nf] = __builtin_amdgcn_mfma_f32_16x16x32_bf16(af, wf, acc[rt][nf], 0, 0, 0);
                }
            }
        }

        int rbase = tile * 64;
#pragma unroll
        for (int rt = 0; rt < 4; ++rt) {
            int orow0 = rbase + rt * 16 + ko * 4;
#pragma unroll
            for (int nf = 0; nf < NFW; ++nf) {
                int col = (wv * NFW + nf) * 16 + lr;
                float bs = bias[col];
#pragma unroll
                for (int j = 0; j < 4; ++j) {
                    int r = orow0 + j;
                    if (r < N_NODES) {
                        float v = acc[rt][nf][j] + bs;
                        if (BF16OUT) hout[(size_t)r * 128 + col] = f2b(v);
                        else         fout[(size_t)r * 64 + col] = v;
                        if (STATS) { sacc[nf] += v; qacc[nf] += v * v; }
                    }
                }
            }
        }
    };

    // ---- 2-phase pipeline ----
    STAGE(0, t0);
    __syncthreads();          // tile0 staged
    STAGE(1, t1);             // overlaps tile0 compute
    COMPUTE(0, t0);
    __syncthreads();          // tile1 staged (DMA had full compute phase)
    COMPUTE(1, t1);

    // ---- stats reduction: one atomic pair per col per block ----
    if (STATS) {
#pragma unroll
        for (int nf = 0; nf < NFW; ++nf) {
            float s = sacc[nf], q = qacc[nf];
            s += __shfl_xor(s, 16);
            s += __shfl_xor(s, 32);
            q += __shfl_xor(q, 16);
            q += __shfl_xor(q, 32);
            if (ko == 0) {
                int col = (wv * NFW + nf) * 16 + lr;
                atomicAdd(&cs[col], s);
                atomicAdd(&cq[col], q);
            }
        }
    }
}

__global__ void bn_prep(const float* __restrict__ cs, const float* __restrict__ cq,
                        const float* __restrict__ g, const float* __restrict__ be,
                        float* __restrict__ scale, float* __restrict__ shift) {
    int f = threadIdx.x;
    float mu = cs[f] * (1.0f / N_NODES);
    float var = cq[f] * (1.0f / N_NODES) - mu * mu;
    float sc = g[f] * rsqrtf(var + BN_EPS);
    scale[f] = sc;
    shift[f] = be[f] - mu * sc;
}

// ---------------------------------------------------------------------------
extern "C" void kernel_launch(void* const* d_in, const int* in_sizes, int n_in,
                              void* d_out, int out_size, void* d_ws, size_t ws_size,
                              hipStream_t stream) {
    const float* x   = (const float*)d_in[0];
    const int*   ei  = (const int*)d_in[1];
    const float* Wl1 = (const float*)d_in[2];
    const float* Wr1 = (const float*)d_in[3];
    const float* b1  = (const float*)d_in[4];
    const float* g1  = (const float*)d_in[5];
    const float* be1 = (const float*)d_in[6];
    const float* Wl2 = (const float*)d_in[7];
    const float* Wr2 = (const float*)d_in[8];
    const float* b2  = (const float*)d_in[9];
    const float* g2  = (const float*)d_in[10];
    const float* be2 = (const float*)d_in[11];
    const float* Wl3 = (const float*)d_in[12];
    const float* Wr3 = (const float*)d_in[13];
    const float* b3  = (const float*)d_in[14];
    float* out = (float*)d_out;

    char* p = (char*)d_ws;
    size_t off = 0;
    auto alloc = [&](size_t bytes) {
        char* r = p + off;
        off = (off + bytes + 255) & ~(size_t)255;
        return r;
    };
    int*            gcur  = (int*)alloc((size_t)NB * 4);
    int*            bbase = (int*)alloc((size_t)NB * 4);
    unsigned int*   bdata = (unsigned int*)alloc((size_t)NB * BCAP * 4);
    int*            row   = (int*)alloc((size_t)(N_NODES + 1) * 4);
    int*            csrc  = (int*)alloc((size_t)N_EDGES * 4);
    unsigned short* xb    = (unsigned short*)alloc((size_t)N_NODES * 128 * 2);
    unsigned short* mn    = (unsigned short*)alloc((size_t)N_NODES * 128 * 2);
    unsigned short* h1    = (unsigned short*)alloc((size_t)N_NODES * 128 * 2);
    unsigned short* h2    = (unsigned short*)alloc((size_t)N_NODES * 128 * 2);
    unsigned short* wpb   = (unsigned short*)alloc((size_t)81920 * 2);
    float*          cs    = (float*)alloc(256 * 4);   // cs[128] | cq[128]
    float*          cq    = cs + 128;
    float*          scl1  = (float*)alloc(128 * 4);
    float*          shf1  = (float*)alloc(128 * 4);
    float*          scl2  = (float*)alloc(128 * 4);
    float*          shf2  = (float*)alloc(128 * 4);
    (void)ws_size; (void)n_in; (void)in_sizes; (void)out_size;

    unsigned short* wp1 = wpb;
    unsigned short* wp2 = wpb + 32768;
    unsigned short* wp3 = wpb + 65536;

    const int NBLK8 = (N_NODES + 7) / 8;            // 6250
    const int CBLK  = (N_NODES * 32 + 255) / 256;   // 6250

    // casts + weight packing + CSR build
    cast_x<<<CBLK, 256, 0, stream>>>(x, xb);
    wpack<<<320, 256, 0, stream>>>(Wl1, Wr1, Wl2, Wr2, Wl3, Wr3, wpb);
    init_gcur<<<1, 256, 0, stream>>>(gcur);
    bucket_scatter<<<SCAT_BLOCKS, 256, 0, stream>>>(ei, gcur, bdata);
    scan_buckets<<<1, 256, 0, stream>>>(gcur, bbase, row);
    bucket_fill<<<NB, 256, 0, stream>>>(bdata, gcur, bbase, row, csrc);

    // Layer 1
    agg_mean_bf16<false><<<NBLK8, 256, 0, stream>>>(xb, row, csrc, nullptr, nullptr, mn);
    hipMemsetAsync(cs, 0, 256 * 4, stream);
    gemm_mfma<128, true, true, false><<<GGRID, 256, 0, stream>>>(
        mn, xb, wp1, b1, nullptr, nullptr, h1, nullptr, cs, cq);
    bn_prep<<<1, 128, 0, stream>>>(cs, cq, g1, be1, scl1, shf1);

    // Layer 2 (h1 raw; BN1+ReLU fused into agg + gemm self-path)
    agg_mean_bf16<true><<<NBLK8, 256, 0, stream>>>(h1, row, csrc, scl1, shf1, mn);
    hipMemsetAsync(cs, 0, 256 * 4, stream);
    gemm_mfma<128, true, true, true><<<GGRID, 256, 0, stream>>>(
        mn, h1, wp2, b2, scl1, shf1, h2, nullptr, cs, cq);
    bn_prep<<<1, 128, 0, stream>>>(cs, cq, g2, be2, scl2, shf2);

    // Layer 3 (h2 raw; BN2+ReLU fused) -> f32 d_out
    agg_mean_bf16<true><<<NBLK8, 256, 0, stream>>>(h2, row, csrc, scl2, shf2, mn);
    gemm_mfma<64, false, false, true><<<GGRID, 256, 0, stream>>>(
        mn, h2, wp3, b3, scl2, shf2, nullptr, out, nullptr, nullptr);
}